// Round 4
// baseline (385.586 us; speedup 1.0000x reference)
//
#include <hip/hip_runtime.h>
#include <hip/hip_bf16.h>

#define D 128
#define NC 5

typedef unsigned int u32;
typedef float f32x4 __attribute__((ext_vector_type(4)));

// ---- Pass 1: per-row int8 quantization (8 lanes/row, 32 rows/block) ----
// Each row (128 f32): absmax -> scale = absmax/127; q = rint(x*127/absmax).
// |x| <= absmax guarantees q in [-127,127], no clamp needed.
__global__ __launch_bounds__(256) void quant_rows_kernel(
    const float* __restrict__ u_feats, const float* __restrict__ v_feats,
    char* __restrict__ q_u, char* __restrict__ q_v,
    float* __restrict__ s_u, float* __restrict__ s_v,
    int nrow_u, int nrow_v)
{
    const int lane = threadIdx.x & 7;
    const int grp  = threadIdx.x >> 3;
    const int row  = blockIdx.x * 32 + grp;
    if (row >= nrow_u + nrow_v) return;

    const float* src; char* qdst; float* sdst; int r;
    if (row < nrow_u) { src = u_feats; qdst = q_u; sdst = s_u; r = row; }
    else              { src = v_feats; qdst = q_v; sdst = s_v; r = row - nrow_u; }

    const f32x4* sp = (const f32x4*)(src + (size_t)r * D);
    f32x4 x0 = sp[lane * 4 + 0];
    f32x4 x1 = sp[lane * 4 + 1];
    f32x4 x2 = sp[lane * 4 + 2];
    f32x4 x3 = sp[lane * 4 + 3];

    float m = 0.f;
    #pragma unroll
    for (int k = 0; k < 4; ++k) {
        m = fmaxf(m, fmaxf(fmaxf(fabsf(x0[k]), fabsf(x1[k])),
                           fmaxf(fabsf(x2[k]), fabsf(x3[k]))));
    }
    #pragma unroll
    for (int off = 4; off > 0; off >>= 1)
        m = fmaxf(m, __shfl_xor(m, off, 8));

    const float inv = 127.0f / fmaxf(m, 1e-30f);

    u32 w0 = 0, w1 = 0, w2 = 0, w3 = 0;
    #pragma unroll
    for (int k = 0; k < 4; ++k) {
        w0 |= ((u32)(unsigned char)(int)rintf(x0[k] * inv)) << (8 * k);
        w1 |= ((u32)(unsigned char)(int)rintf(x1[k] * inv)) << (8 * k);
        w2 |= ((u32)(unsigned char)(int)rintf(x2[k] * inv)) << (8 * k);
        w3 |= ((u32)(unsigned char)(int)rintf(x3[k] * inv)) << (8 * k);
    }
    ((uint4*)(qdst + (size_t)r * D))[lane] = make_uint4(w0, w1, w2, w3);
    if (lane == 0) sdst[r] = m * (1.0f / 127.0f);
}

// ---- Pass 2: int8 gathers (128B/row), exact f32 W/scalars/bias ----
// Fabric-byte-limited regime (measured ~3.86 TB/s TCC-miss plateau):
// halving gather bytes is the lever; VALU per dim stays ~8 ops.
__global__ __launch_bounds__(256) void bilinear_i8_kernel(
    const char*  __restrict__ q_u,     // [NUM_USERS,128] int8 (ws)
    const char*  __restrict__ q_v,     // [NUM_ITEMS,128] int8 (ws)
    const float* __restrict__ s_u,     // [NUM_USERS] f32 row scales (ws)
    const float* __restrict__ s_v,     // [NUM_ITEMS] f32 row scales (ws)
    const float* __restrict__ W,       // [3,128] f32 (original input)
    const int*   __restrict__ u_idx,
    const int*   __restrict__ v_idx,
    const float* __restrict__ scalars, // [3,5] f32
    const float* __restrict__ u_bias,  // [*,5] f32
    const float* __restrict__ v_bias,  // [*,5] f32
    float* __restrict__ out,           // [E,5] f32
    int E)
{
    const int lane = threadIdx.x & 7;    // 8 lanes/edge: 16 int8 (16B) each
    const int grp  = threadIdx.x >> 3;   // 32 edges per 256-thread block
    const int e    = blockIdx.x * 32 + grp;
    if (e >= E) return;

    const int ui = __builtin_nontemporal_load(u_idx + e);
    const int vi = __builtin_nontemporal_load(v_idx + e);

    // 2 random 16B gathers per lane (8 lanes -> one 128B row each).
    const uint4 qu = *(const uint4*)(q_u + (size_t)ui * D + lane * 16);
    const uint4 qv = *(const uint4*)(q_v + (size_t)vi * D + lane * 16);

    // Row scales: 400KB tables, L2-resident; broadcast within group.
    const float su = s_u[ui];
    const float sv = s_v[vi];

    // Bias gathers early (overlap row gathers).
    float bsum = 0.f, sc0 = 0.f, sc1 = 0.f, sc2 = 0.f;
    if (lane < NC) {
        bsum = u_bias[(size_t)ui * NC + lane] + v_bias[(size_t)vi * NC + lane];
        sc0 = scalars[0 * NC + lane];
        sc1 = scalars[1 * NC + lane];
        sc2 = scalars[2 * NC + lane];
    }

    // W in f32 registers: lane's 16 dims x 3 bases (L1-hot, 768B table).
    const f32x4* Wp = (const f32x4*)W;   // 32 f32x4 per basis row
    f32x4 wa[4], wb[4], wc[4];
    #pragma unroll
    for (int k = 0; k < 4; ++k) {
        wa[k] = Wp[ 0 + lane * 4 + k];
        wb[k] = Wp[32 + lane * 4 + k];
        wc[k] = Wp[64 + lane * 4 + k];
    }

    float s0 = 0.f, s1 = 0.f, s2 = 0.f;
    #pragma unroll
    for (int k = 0; k < 4; ++k) {
        const u32 a = (&qu.x)[k];
        const u32 b = (&qv.x)[k];
        #pragma unroll
        for (int j = 0; j < 4; ++j) {
            const int au = (int)(signed char)(a >> (8 * j));   // v_bfe_i32
            const int av = (int)(signed char)(b >> (8 * j));
            const float p = (float)au * (float)av;
            s0 = fmaf(p, wa[k][j], s0);
            s1 = fmaf(p, wb[k][j], s1);
            s2 = fmaf(p, wc[k][j], s2);
        }
    }

    // Reduce across the 8-lane group (3 steps).
    #pragma unroll
    for (int off = 4; off > 0; off >>= 1) {
        s0 += __shfl_xor(s0, off, 8);
        s1 += __shfl_xor(s1, off, 8);
        s2 += __shfl_xor(s2, off, 8);
    }

    if (lane < NC) {
        const float sc = su * sv;        // fold both row scales once
        const float r = sc * (s0 * sc0 + s1 * sc1 + s2 * sc2) + bsum;
        __builtin_nontemporal_store(r, out + (size_t)e * NC + lane);
    }
}

// ---- Fallback (f32 gathers) if ws too small ----
__global__ __launch_bounds__(256) void bilinear_f32_kernel(
    const float* __restrict__ u_feats, const float* __restrict__ v_feats,
    const int* __restrict__ u_idx, const int* __restrict__ v_idx,
    const float* __restrict__ W, const float* __restrict__ scalars,
    const float* __restrict__ u_bias, const float* __restrict__ v_bias,
    float* __restrict__ out, int E)
{
    const int lane = threadIdx.x & 15;
    const int grp  = threadIdx.x >> 4;
    const int e    = blockIdx.x * 16 + grp;
    if (e >= E) return;
    const int ui = u_idx[e];
    const int vi = v_idx[e];
    const float4* ur = (const float4*)(u_feats + (size_t)ui * D);
    const float4* vr = (const float4*)(v_feats + (size_t)vi * D);
    const float4* Wr = (const float4*)W;
    float4 ua0 = ur[lane*2+0], ua1 = ur[lane*2+1];
    float4 va0 = vr[lane*2+0], va1 = vr[lane*2+1];
    float4 w00 = Wr[ 0+lane*2], w01 = Wr[ 1+lane*2];
    float4 w10 = Wr[32+lane*2], w11 = Wr[33+lane*2];
    float4 w20 = Wr[64+lane*2], w21 = Wr[65+lane*2];
    float s0=0.f, s1=0.f, s2=0.f;
    #pragma unroll
    for (int k = 0; k < 4; ++k) {
        float p = (&ua0.x)[k] * (&va0.x)[k];
        s0 = fmaf(p, (&w00.x)[k], s0);
        s1 = fmaf(p, (&w10.x)[k], s1);
        s2 = fmaf(p, (&w20.x)[k], s2);
    }
    #pragma unroll
    for (int k = 0; k < 4; ++k) {
        float p = (&ua1.x)[k] * (&va1.x)[k];
        s0 = fmaf(p, (&w01.x)[k], s0);
        s1 = fmaf(p, (&w11.x)[k], s1);
        s2 = fmaf(p, (&w21.x)[k], s2);
    }
    #pragma unroll
    for (int off = 8; off > 0; off >>= 1) {
        s0 += __shfl_xor(s0, off, 16);
        s1 += __shfl_xor(s1, off, 16);
        s2 += __shfl_xor(s2, off, 16);
    }
    if (lane < NC) {
        float r = s0*scalars[0*NC+lane] + s1*scalars[1*NC+lane] + s2*scalars[2*NC+lane]
                + u_bias[(size_t)ui*NC+lane] + v_bias[(size_t)vi*NC+lane];
        out[(size_t)e*NC+lane] = r;
    }
}

extern "C" void kernel_launch(void* const* d_in, const int* in_sizes, int n_in,
                              void* d_out, int out_size, void* d_ws, size_t ws_size,
                              hipStream_t stream) {
    const float* u_feats = (const float*)d_in[0];
    const float* v_feats = (const float*)d_in[1];
    const int*   u_idx   = (const int*)d_in[2];
    const int*   v_idx   = (const int*)d_in[3];
    const float* W       = (const float*)d_in[4];
    const float* scalars = (const float*)d_in[5];
    const float* u_bias  = (const float*)d_in[6];
    const float* v_bias  = (const float*)d_in[7];
    float* out           = (float*)d_out;

    const int nu = in_sizes[0];   // NUM_USERS * 128
    const int nv = in_sizes[1];   // NUM_ITEMS * 128
    const int E  = in_sizes[2];
    const int nrow_u = nu / D;
    const int nrow_v = nv / D;

    // ws layout: q_u[nu] int8 | q_v[nv] int8 | s_u[nrow_u] f32 | s_v[nrow_v] f32
    const size_t need = (size_t)nu + (size_t)nv
                      + sizeof(float) * ((size_t)nrow_u + (size_t)nrow_v);
    if (ws_size >= need) {
        char*  q_u = (char*)d_ws;
        char*  q_v = q_u + nu;
        float* s_u = (float*)(q_v + nv);
        float* s_v = s_u + nrow_u;
        const int rows = nrow_u + nrow_v;
        quant_rows_kernel<<<(rows + 31) / 32, 256, 0, stream>>>(
            u_feats, v_feats, q_u, q_v, s_u, s_v, nrow_u, nrow_v);
        bilinear_i8_kernel<<<(E + 31) / 32, 256, 0, stream>>>(
            q_u, q_v, s_u, s_v, W, u_idx, v_idx, scalars, u_bias, v_bias, out, E);
    } else {
        bilinear_f32_kernel<<<(E + 15) / 16, 256, 0, stream>>>(
            u_feats, v_feats, u_idx, v_idx, W, scalars, u_bias, v_bias, out, E);
    }
}

// Round 5
// 300.309 us; speedup vs baseline: 1.2840x; 1.2840x over previous
//
#include <hip/hip_runtime.h>
#include <hip/hip_bf16.h>

#define D 128
#define NC 5

typedef unsigned int u32;
typedef float f32x4 __attribute__((ext_vector_type(4)));

// ---- Pass 1: per-row int8 quantization (8 lanes/row, 32 rows/block) ----
// Each row (128 f32): absmax -> scale = absmax/127; q = rint(x*127/absmax).
__global__ __launch_bounds__(256) void quant_rows_kernel(
    const float* __restrict__ u_feats, const float* __restrict__ v_feats,
    char* __restrict__ q_u, char* __restrict__ q_v,
    float* __restrict__ s_u, float* __restrict__ s_v,
    int nrow_u, int nrow_v)
{
    const int lane = threadIdx.x & 7;
    const int grp  = threadIdx.x >> 3;
    const int row  = blockIdx.x * 32 + grp;
    if (row >= nrow_u + nrow_v) return;

    const float* src; char* qdst; float* sdst; int r;
    if (row < nrow_u) { src = u_feats; qdst = q_u; sdst = s_u; r = row; }
    else              { src = v_feats; qdst = q_v; sdst = s_v; r = row - nrow_u; }

    const f32x4* sp = (const f32x4*)(src + (size_t)r * D);
    f32x4 x0 = sp[lane * 4 + 0];
    f32x4 x1 = sp[lane * 4 + 1];
    f32x4 x2 = sp[lane * 4 + 2];
    f32x4 x3 = sp[lane * 4 + 3];

    float m = 0.f;
    #pragma unroll
    for (int k = 0; k < 4; ++k) {
        m = fmaxf(m, fmaxf(fmaxf(fabsf(x0[k]), fabsf(x1[k])),
                           fmaxf(fabsf(x2[k]), fabsf(x3[k]))));
    }
    #pragma unroll
    for (int off = 4; off > 0; off >>= 1)
        m = fmaxf(m, __shfl_xor(m, off, 8));

    const float inv = 127.0f / fmaxf(m, 1e-30f);

    u32 w0 = 0, w1 = 0, w2 = 0, w3 = 0;
    #pragma unroll
    for (int k = 0; k < 4; ++k) {
        w0 |= ((u32)(unsigned char)(int)rintf(x0[k] * inv)) << (8 * k);
        w1 |= ((u32)(unsigned char)(int)rintf(x1[k] * inv)) << (8 * k);
        w2 |= ((u32)(unsigned char)(int)rintf(x2[k] * inv)) << (8 * k);
        w3 |= ((u32)(unsigned char)(int)rintf(x3[k] * inv)) << (8 * k);
    }
    ((uint4*)(qdst + (size_t)r * D))[lane] = make_uint4(w0, w1, w2, w3);
    if (lane == 0) sdst[r] = m * (1.0f / 127.0f);
}

// ---- Pass 2: int8 gathers, 2 edges per 8-lane group ----
// Measured law (R0/R1/R4): delivered gather BW ~ proportional to outstanding
// row-gather loads per lane, capped ~3.9 TB/s. 4 gathers/lane reaches the
// cap (bf16 x1 proved it); int8 halves the bytes. 2 edges/group restores
// 4 in-flight gathers while keeping the 128B rows.
__global__ __launch_bounds__(256) void bilinear_i8x2_kernel(
    const char*  __restrict__ q_u,     // [NUM_USERS,128] int8 (ws)
    const char*  __restrict__ q_v,     // [NUM_ITEMS,128] int8 (ws)
    const float* __restrict__ s_u,     // [NUM_USERS] f32 row scales (ws)
    const float* __restrict__ s_v,     // [NUM_ITEMS] f32 row scales (ws)
    const float* __restrict__ W,       // [3,128] f32 (original input, exact)
    const int*   __restrict__ u_idx,
    const int*   __restrict__ v_idx,
    const float* __restrict__ scalars, // [3,5] f32
    const float* __restrict__ u_bias,  // [*,5] f32
    const float* __restrict__ v_bias,  // [*,5] f32
    float* __restrict__ out,           // [E,5] f32
    int E)
{
    const int lane = threadIdx.x & 7;    // 8 lanes/edge: 16 int8 (16B) each
    const int grp  = threadIdx.x >> 3;   // 0..31
    const int base = blockIdx.x * 64;
    const int e0   = base + grp;
    if (e0 >= E) return;
    const int e1r  = base + 32 + grp;
    const bool has1 = (e1r < E);
    const int e1   = has1 ? e1r : e0;    // clamp: duplicate work, store guarded

    const int ui0 = __builtin_nontemporal_load(u_idx + e0);
    const int vi0 = __builtin_nontemporal_load(v_idx + e0);
    const int ui1 = __builtin_nontemporal_load(u_idx + e1);
    const int vi1 = __builtin_nontemporal_load(v_idx + e1);

    // 4 independent random 16B gathers in flight per lane.
    const uint4 qu0 = *(const uint4*)(q_u + (size_t)ui0 * D + lane * 16);
    const uint4 qv0 = *(const uint4*)(q_v + (size_t)vi0 * D + lane * 16);
    const uint4 qu1 = *(const uint4*)(q_u + (size_t)ui1 * D + lane * 16);
    const uint4 qv1 = *(const uint4*)(q_v + (size_t)vi1 * D + lane * 16);

    // Row scales (800KB total, L2-resident; broadcast within group).
    const float su0 = s_u[ui0], sv0 = s_v[vi0];
    const float su1 = s_u[ui1], sv1 = s_v[vi1];

    // Bias gathers early (overlap row gathers).
    float bs0 = 0.f, bs1 = 0.f, sc0 = 0.f, sc1 = 0.f, sc2 = 0.f;
    if (lane < NC) {
        bs0 = u_bias[(size_t)ui0 * NC + lane] + v_bias[(size_t)vi0 * NC + lane];
        bs1 = u_bias[(size_t)ui1 * NC + lane] + v_bias[(size_t)vi1 * NC + lane];
        sc0 = scalars[0 * NC + lane];
        sc1 = scalars[1 * NC + lane];
        sc2 = scalars[2 * NC + lane];
    }

    // W in f32 registers: lane's 16 dims x 3 bases (L1-hot, 1.5KB table),
    // shared across both edges.
    const f32x4* Wp = (const f32x4*)W;   // 32 f32x4 per basis row
    f32x4 wa[4], wb[4], wc[4];
    #pragma unroll
    for (int k = 0; k < 4; ++k) {
        wa[k] = Wp[ 0 + lane * 4 + k];
        wb[k] = Wp[32 + lane * 4 + k];
        wc[k] = Wp[64 + lane * 4 + k];
    }

    float a0 = 0.f, a1 = 0.f, a2 = 0.f;
    float b0 = 0.f, b1 = 0.f, b2 = 0.f;
    #pragma unroll
    for (int k = 0; k < 4; ++k) {
        const u32 A0 = (&qu0.x)[k], B0 = (&qv0.x)[k];
        const u32 A1 = (&qu1.x)[k], B1 = (&qv1.x)[k];
        #pragma unroll
        for (int j = 0; j < 4; ++j) {
            const float w0 = wa[k][j], w1 = wb[k][j], w2 = wc[k][j];
            {
                const int au = (int)(signed char)(A0 >> (8 * j));  // v_bfe_i32
                const int av = (int)(signed char)(B0 >> (8 * j));
                const float p = (float)au * (float)av;
                a0 = fmaf(p, w0, a0);
                a1 = fmaf(p, w1, a1);
                a2 = fmaf(p, w2, a2);
            }
            {
                const int au = (int)(signed char)(A1 >> (8 * j));
                const int av = (int)(signed char)(B1 >> (8 * j));
                const float p = (float)au * (float)av;
                b0 = fmaf(p, w0, b0);
                b1 = fmaf(p, w1, b1);
                b2 = fmaf(p, w2, b2);
            }
        }
    }

    // Reduce across the 8-lane group (3 steps, 6 accumulators).
    #pragma unroll
    for (int off = 4; off > 0; off >>= 1) {
        a0 += __shfl_xor(a0, off, 8);
        a1 += __shfl_xor(a1, off, 8);
        a2 += __shfl_xor(a2, off, 8);
        b0 += __shfl_xor(b0, off, 8);
        b1 += __shfl_xor(b1, off, 8);
        b2 += __shfl_xor(b2, off, 8);
    }

    if (lane < NC) {
        const float r0 = (su0 * sv0) * (a0 * sc0 + a1 * sc1 + a2 * sc2) + bs0;
        __builtin_nontemporal_store(r0, out + (size_t)e0 * NC + lane);
        if (has1) {
            const float r1 = (su1 * sv1) * (b0 * sc0 + b1 * sc1 + b2 * sc2) + bs1;
            __builtin_nontemporal_store(r1, out + (size_t)e1 * NC + lane);
        }
    }
}

// ---- Fallback (f32 gathers) if ws too small ----
__global__ __launch_bounds__(256) void bilinear_f32_kernel(
    const float* __restrict__ u_feats, const float* __restrict__ v_feats,
    const int* __restrict__ u_idx, const int* __restrict__ v_idx,
    const float* __restrict__ W, const float* __restrict__ scalars,
    const float* __restrict__ u_bias, const float* __restrict__ v_bias,
    float* __restrict__ out, int E)
{
    const int lane = threadIdx.x & 15;
    const int grp  = threadIdx.x >> 4;
    const int e    = blockIdx.x * 16 + grp;
    if (e >= E) return;
    const int ui = u_idx[e];
    const int vi = v_idx[e];
    const float4* ur = (const float4*)(u_feats + (size_t)ui * D);
    const float4* vr = (const float4*)(v_feats + (size_t)vi * D);
    const float4* Wr = (const float4*)W;
    float4 ua0 = ur[lane*2+0], ua1 = ur[lane*2+1];
    float4 va0 = vr[lane*2+0], va1 = vr[lane*2+1];
    float4 w00 = Wr[ 0+lane*2], w01 = Wr[ 1+lane*2];
    float4 w10 = Wr[32+lane*2], w11 = Wr[33+lane*2];
    float4 w20 = Wr[64+lane*2], w21 = Wr[65+lane*2];
    float s0=0.f, s1=0.f, s2=0.f;
    #pragma unroll
    for (int k = 0; k < 4; ++k) {
        float p = (&ua0.x)[k] * (&va0.x)[k];
        s0 = fmaf(p, (&w00.x)[k], s0);
        s1 = fmaf(p, (&w10.x)[k], s1);
        s2 = fmaf(p, (&w20.x)[k], s2);
    }
    #pragma unroll
    for (int k = 0; k < 4; ++k) {
        float p = (&ua1.x)[k] * (&va1.x)[k];
        s0 = fmaf(p, (&w01.x)[k], s0);
        s1 = fmaf(p, (&w11.x)[k], s1);
        s2 = fmaf(p, (&w21.x)[k], s2);
    }
    #pragma unroll
    for (int off = 8; off > 0; off >>= 1) {
        s0 += __shfl_xor(s0, off, 16);
        s1 += __shfl_xor(s1, off, 16);
        s2 += __shfl_xor(s2, off, 16);
    }
    if (lane < NC) {
        float r = s0*scalars[0*NC+lane] + s1*scalars[1*NC+lane] + s2*scalars[2*NC+lane]
                + u_bias[(size_t)ui*NC+lane] + v_bias[(size_t)vi*NC+lane];
        out[(size_t)e*NC+lane] = r;
    }
}

extern "C" void kernel_launch(void* const* d_in, const int* in_sizes, int n_in,
                              void* d_out, int out_size, void* d_ws, size_t ws_size,
                              hipStream_t stream) {
    const float* u_feats = (const float*)d_in[0];
    const float* v_feats = (const float*)d_in[1];
    const int*   u_idx   = (const int*)d_in[2];
    const int*   v_idx   = (const int*)d_in[3];
    const float* W       = (const float*)d_in[4];
    const float* scalars = (const float*)d_in[5];
    const float* u_bias  = (const float*)d_in[6];
    const float* v_bias  = (const float*)d_in[7];
    float* out           = (float*)d_out;

    const int nu = in_sizes[0];   // NUM_USERS * 128
    const int nv = in_sizes[1];   // NUM_ITEMS * 128
    const int E  = in_sizes[2];
    const int nrow_u = nu / D;
    const int nrow_v = nv / D;

    // ws layout: q_u[nu] int8 | q_v[nv] int8 | s_u[nrow_u] f32 | s_v[nrow_v] f32
    const size_t need = (size_t)nu + (size_t)nv
                      + sizeof(float) * ((size_t)nrow_u + (size_t)nrow_v);
    if (ws_size >= need) {
        char*  q_u = (char*)d_ws;
        char*  q_v = q_u + nu;
        float* s_u = (float*)(q_v + nv);
        float* s_v = s_u + nrow_u;
        const int rows = nrow_u + nrow_v;
        quant_rows_kernel<<<(rows + 31) / 32, 256, 0, stream>>>(
            u_feats, v_feats, q_u, q_v, s_u, s_v, nrow_u, nrow_v);
        bilinear_i8x2_kernel<<<(E + 63) / 64, 256, 0, stream>>>(
            q_u, q_v, s_u, s_v, W, u_idx, v_idx, scalars, u_bias, v_bias, out, E);
    } else {
        bilinear_f32_kernel<<<(E + 15) / 16, 256, 0, stream>>>(
            u_feats, v_feats, u_idx, v_idx, W, scalars, u_bias, v_bias, out, E);
    }
}

// Round 6
// 282.579 us; speedup vs baseline: 1.3645x; 1.0627x over previous
//
#include <hip/hip_runtime.h>
#include <hip/hip_bf16.h>

#define D 128
#define NC 5

typedef unsigned int u32;
typedef float f32x4 __attribute__((ext_vector_type(4)));

// ---- Pass 1: per-row int8 quantization (8 lanes/row, 32 rows/block) ----
__global__ __launch_bounds__(256) void quant_rows_kernel(
    const float* __restrict__ u_feats, const float* __restrict__ v_feats,
    char* __restrict__ q_u, char* __restrict__ q_v,
    float* __restrict__ s_u, float* __restrict__ s_v,
    int nrow_u, int nrow_v)
{
    const int lane = threadIdx.x & 7;
    const int grp  = threadIdx.x >> 3;
    const int row  = blockIdx.x * 32 + grp;
    if (row >= nrow_u + nrow_v) return;

    const float* src; char* qdst; float* sdst; int r;
    if (row < nrow_u) { src = u_feats; qdst = q_u; sdst = s_u; r = row; }
    else              { src = v_feats; qdst = q_v; sdst = s_v; r = row - nrow_u; }

    const f32x4* sp = (const f32x4*)(src + (size_t)r * D);
    f32x4 x0 = sp[lane * 4 + 0];
    f32x4 x1 = sp[lane * 4 + 1];
    f32x4 x2 = sp[lane * 4 + 2];
    f32x4 x3 = sp[lane * 4 + 3];

    float m = 0.f;
    #pragma unroll
    for (int k = 0; k < 4; ++k) {
        m = fmaxf(m, fmaxf(fmaxf(fabsf(x0[k]), fabsf(x1[k])),
                           fmaxf(fabsf(x2[k]), fabsf(x3[k]))));
    }
    #pragma unroll
    for (int off = 4; off > 0; off >>= 1)
        m = fmaxf(m, __shfl_xor(m, off, 8));

    const float inv = 127.0f / fmaxf(m, 1e-30f);

    u32 w0 = 0, w1 = 0, w2 = 0, w3 = 0;
    #pragma unroll
    for (int k = 0; k < 4; ++k) {
        w0 |= ((u32)(unsigned char)(int)rintf(x0[k] * inv)) << (8 * k);
        w1 |= ((u32)(unsigned char)(int)rintf(x1[k] * inv)) << (8 * k);
        w2 |= ((u32)(unsigned char)(int)rintf(x2[k] * inv)) << (8 * k);
        w3 |= ((u32)(unsigned char)(int)rintf(x3[k] * inv)) << (8 * k);
    }
    ((uint4*)(qdst + (size_t)r * D))[lane] = make_uint4(w0, w1, w2, w3);
    if (lane == 0) sdst[r] = m * (1.0f / 127.0f);
}

// ---- Pass 2: int8 gathers, 4 edges per 8-lane group (8 gathers/lane) ----
// Measured law (R0/R1/R4/R5): delivered gather BW ~ occupancy x in-flight
// gathers/lane, saturating ~3.86 TB/s around product >= ~250.
// i8x2 sat at 42% x 4 = 170 -> 3.2 TB/s; 8/lane pushes onto the plateau
// even at ~35-40% occupancy (bf16x2: 40% x 8 -> 3.8 TB/s).
__global__ __launch_bounds__(256) void bilinear_i8x4_kernel(
    const char*  __restrict__ q_u,     // [NUM_USERS,128] int8 (ws)
    const char*  __restrict__ q_v,     // [NUM_ITEMS,128] int8 (ws)
    const float* __restrict__ s_u,     // [NUM_USERS] f32 row scales (ws)
    const float* __restrict__ s_v,     // [NUM_ITEMS] f32 row scales (ws)
    const float* __restrict__ W,       // [3,128] f32 (original input, exact)
    const int*   __restrict__ u_idx,
    const int*   __restrict__ v_idx,
    const float* __restrict__ scalars, // [3,5] f32
    const float* __restrict__ u_bias,  // [*,5] f32
    const float* __restrict__ v_bias,  // [*,5] f32
    float* __restrict__ out,           // [E,5] f32
    int E)
{
    const int lane = threadIdx.x & 7;    // 8 lanes/edge: 16 int8 (16B) each
    const int grp  = threadIdx.x >> 3;   // 0..31
    const int base = blockIdx.x * 128;   // 128 edges/block
    if (base + grp >= E) return;

    int e[4];
    bool has[4];
    #pragma unroll
    for (int t = 0; t < 4; ++t) {
        const int et = base + 32 * t + grp;
        has[t] = (et < E);
        e[t] = has[t] ? et : (base + grp);   // clamp: dup work, store guarded
    }

    int ui[4], vi[4];
    #pragma unroll
    for (int t = 0; t < 4; ++t) {
        ui[t] = __builtin_nontemporal_load(u_idx + e[t]);
        vi[t] = __builtin_nontemporal_load(v_idx + e[t]);
    }

    // 8 independent random 16B gathers in flight per lane.
    uint4 qu[4], qv[4];
    #pragma unroll
    for (int t = 0; t < 4; ++t) {
        qu[t] = *(const uint4*)(q_u + (size_t)ui[t] * D + lane * 16);
        qv[t] = *(const uint4*)(q_v + (size_t)vi[t] * D + lane * 16);
    }

    // Row scales (800KB total, mostly L2-resident).
    float ss[4];
    #pragma unroll
    for (int t = 0; t < 4; ++t) ss[t] = s_u[ui[t]] * s_v[vi[t]];

    // Bias gathers early (overlap row gathers).
    float bs[4] = {0.f, 0.f, 0.f, 0.f};
    float sc0 = 0.f, sc1 = 0.f, sc2 = 0.f;
    if (lane < NC) {
        #pragma unroll
        for (int t = 0; t < 4; ++t)
            bs[t] = u_bias[(size_t)ui[t] * NC + lane]
                  + v_bias[(size_t)vi[t] * NC + lane];
        sc0 = scalars[0 * NC + lane];
        sc1 = scalars[1 * NC + lane];
        sc2 = scalars[2 * NC + lane];
    }

    // W in f32 registers: lane's 16 dims x 3 bases, shared across 4 edges.
    const f32x4* Wp = (const f32x4*)W;   // 32 f32x4 per basis row
    f32x4 wa[4], wb[4], wc[4];
    #pragma unroll
    for (int k = 0; k < 4; ++k) {
        wa[k] = Wp[ 0 + lane * 4 + k];
        wb[k] = Wp[32 + lane * 4 + k];
        wc[k] = Wp[64 + lane * 4 + k];
    }

    float acc[4][3];
    #pragma unroll
    for (int t = 0; t < 4; ++t) { acc[t][0] = acc[t][1] = acc[t][2] = 0.f; }

    #pragma unroll
    for (int k = 0; k < 4; ++k) {
        #pragma unroll
        for (int j = 0; j < 4; ++j) {
            const float w0 = wa[k][j], w1 = wb[k][j], w2 = wc[k][j];
            #pragma unroll
            for (int t = 0; t < 4; ++t) {
                const int au = (int)(signed char)((&qu[t].x)[k] >> (8 * j));
                const int av = (int)(signed char)((&qv[t].x)[k] >> (8 * j));
                const float p = (float)au * (float)av;
                acc[t][0] = fmaf(p, w0, acc[t][0]);
                acc[t][1] = fmaf(p, w1, acc[t][1]);
                acc[t][2] = fmaf(p, w2, acc[t][2]);
            }
        }
    }

    // Reduce across the 8-lane group (3 steps, 12 accumulators).
    #pragma unroll
    for (int off = 4; off > 0; off >>= 1) {
        #pragma unroll
        for (int t = 0; t < 4; ++t) {
            acc[t][0] += __shfl_xor(acc[t][0], off, 8);
            acc[t][1] += __shfl_xor(acc[t][1], off, 8);
            acc[t][2] += __shfl_xor(acc[t][2], off, 8);
        }
    }

    if (lane < NC) {
        #pragma unroll
        for (int t = 0; t < 4; ++t) {
            if (has[t]) {
                const float r = ss[t] * (acc[t][0] * sc0 + acc[t][1] * sc1
                                       + acc[t][2] * sc2) + bs[t];
                __builtin_nontemporal_store(r, out + (size_t)e[t] * NC + lane);
            }
        }
    }
}

// ---- Fallback (f32 gathers) if ws too small ----
__global__ __launch_bounds__(256) void bilinear_f32_kernel(
    const float* __restrict__ u_feats, const float* __restrict__ v_feats,
    const int* __restrict__ u_idx, const int* __restrict__ v_idx,
    const float* __restrict__ W, const float* __restrict__ scalars,
    const float* __restrict__ u_bias, const float* __restrict__ v_bias,
    float* __restrict__ out, int E)
{
    const int lane = threadIdx.x & 15;
    const int grp  = threadIdx.x >> 4;
    const int e    = blockIdx.x * 16 + grp;
    if (e >= E) return;
    const int ui = u_idx[e];
    const int vi = v_idx[e];
    const float4* ur = (const float4*)(u_feats + (size_t)ui * D);
    const float4* vr = (const float4*)(v_feats + (size_t)vi * D);
    const float4* Wr = (const float4*)W;
    float4 ua0 = ur[lane*2+0], ua1 = ur[lane*2+1];
    float4 va0 = vr[lane*2+0], va1 = vr[lane*2+1];
    float4 w00 = Wr[ 0+lane*2], w01 = Wr[ 1+lane*2];
    float4 w10 = Wr[32+lane*2], w11 = Wr[33+lane*2];
    float4 w20 = Wr[64+lane*2], w21 = Wr[65+lane*2];
    float s0=0.f, s1=0.f, s2=0.f;
    #pragma unroll
    for (int k = 0; k < 4; ++k) {
        float p = (&ua0.x)[k] * (&va0.x)[k];
        s0 = fmaf(p, (&w00.x)[k], s0);
        s1 = fmaf(p, (&w10.x)[k], s1);
        s2 = fmaf(p, (&w20.x)[k], s2);
    }
    #pragma unroll
    for (int k = 0; k < 4; ++k) {
        float p = (&ua1.x)[k] * (&va1.x)[k];
        s0 = fmaf(p, (&w01.x)[k], s0);
        s1 = fmaf(p, (&w11.x)[k], s1);
        s2 = fmaf(p, (&w21.x)[k], s2);
    }
    #pragma unroll
    for (int off = 8; off > 0; off >>= 1) {
        s0 += __shfl_xor(s0, off, 16);
        s1 += __shfl_xor(s1, off, 16);
        s2 += __shfl_xor(s2, off, 16);
    }
    if (lane < NC) {
        float r = s0*scalars[0*NC+lane] + s1*scalars[1*NC+lane] + s2*scalars[2*NC+lane]
                + u_bias[(size_t)ui*NC+lane] + v_bias[(size_t)vi*NC+lane];
        out[(size_t)e*NC+lane] = r;
    }
}

extern "C" void kernel_launch(void* const* d_in, const int* in_sizes, int n_in,
                              void* d_out, int out_size, void* d_ws, size_t ws_size,
                              hipStream_t stream) {
    const float* u_feats = (const float*)d_in[0];
    const float* v_feats = (const float*)d_in[1];
    const int*   u_idx   = (const int*)d_in[2];
    const int*   v_idx   = (const int*)d_in[3];
    const float* W       = (const float*)d_in[4];
    const float* scalars = (const float*)d_in[5];
    const float* u_bias  = (const float*)d_in[6];
    const float* v_bias  = (const float*)d_in[7];
    float* out           = (float*)d_out;

    const int nu = in_sizes[0];   // NUM_USERS * 128
    const int nv = in_sizes[1];   // NUM_ITEMS * 128
    const int E  = in_sizes[2];
    const int nrow_u = nu / D;
    const int nrow_v = nv / D;

    // ws layout: q_u[nu] int8 | q_v[nv] int8 | s_u[nrow_u] f32 | s_v[nrow_v] f32
    const size_t need = (size_t)nu + (size_t)nv
                      + sizeof(float) * ((size_t)nrow_u + (size_t)nrow_v);
    if (ws_size >= need) {
        char*  q_u = (char*)d_ws;
        char*  q_v = q_u + nu;
        float* s_u = (float*)(q_v + nv);
        float* s_v = s_u + nrow_u;
        const int rows = nrow_u + nrow_v;
        quant_rows_kernel<<<(rows + 31) / 32, 256, 0, stream>>>(
            u_feats, v_feats, q_u, q_v, s_u, s_v, nrow_u, nrow_v);
        bilinear_i8x4_kernel<<<(E + 127) / 128, 256, 0, stream>>>(
            q_u, q_v, s_u, s_v, W, u_idx, v_idx, scalars, u_bias, v_bias, out, E);
    } else {
        bilinear_f32_kernel<<<(E + 15) / 16, 256, 0, stream>>>(
            u_feats, v_feats, u_idx, v_idx, W, scalars, u_bias, v_bias, out, E);
    }
}